// Round 5
// baseline (121.924 us; speedup 1.0000x reference)
//
#include <hip/hip_runtime.h>
#include <math.h>

#define B_ 4
#define T_ 512
#define D_ 64
#define EPS 1e-8f

__device__ __forceinline__ float wave_sum(float v) {
#pragma unroll
  for (int m = 1; m < 64; m <<= 1) v += __shfl_xor(v, m, 64);
  return v;
}
__device__ __forceinline__ float wave_max(float v) {
#pragma unroll
  for (int m = 1; m < 64; m <<= 1) v = fmaxf(v, __shfl_xor(v, m, 64));
  return v;
}
__device__ __forceinline__ float softplus_f(float x) {
  return fmaxf(x, 0.0f) + __logf(1.0f + __expf(-fabsf(x)));
}
// acos(x), x in [0,1): A&S 4.4.45, |err| <= 6.8e-5 rad.
__device__ __forceinline__ float acos_fast(float x) {
  float r = fmaf(x, -0.0187293f, 0.0742610f);
  r = fmaf(r, x, -0.2121144f);
  r = fmaf(r, x, 1.5707288f);
  return r * sqrtf(1.0f - x);
}

// ---- logits: 64x64 tile of -2*acos(clip(s_i . s_j)), 512 thr (8 waves) ----
// COMPUTE_S: derive the needed 128 s-rows from x in-kernel (saves the proj
// launch); else read precomputed s. GEMM: thread=(dh,j4,i4), 4x4 reg tile
// over 32 d, shfl_xor(1) combines d-halves.
template <bool COMPUTE_S>
__global__ __launch_bounds__(512) void logits_kernel(const float* __restrict__ xs,
                                                     float* __restrict__ L) {
  int jt = blockIdx.x, it = blockIdx.y, b = blockIdx.z;
  __shared__ float si[64 * 68];
  __shared__ float sj[64 * 68];
  int tid = threadIdx.x;
  const float* sb = xs + (size_t)b * T_ * D_;

  if (COMPUTE_S) {
    // thread = (row 0..127, q: d-quarter). softplus + double-normalize.
    int row = tid >> 2, q = tid & 3;
    int grow = (row < 64) ? (it * 64 + row) : (jt * 64 + (row - 64));
    const float4* xr = (const float4*)(sb + grow * D_ + q * 16);
    float sp[16];
    float4 v0 = xr[0], v1 = xr[1], v2 = xr[2], v3 = xr[3];
    sp[0] = softplus_f(v0.x); sp[1] = softplus_f(v0.y);
    sp[2] = softplus_f(v0.z); sp[3] = softplus_f(v0.w);
    sp[4] = softplus_f(v1.x); sp[5] = softplus_f(v1.y);
    sp[6] = softplus_f(v1.z); sp[7] = softplus_f(v1.w);
    sp[8] = softplus_f(v2.x); sp[9] = softplus_f(v2.y);
    sp[10] = softplus_f(v2.z); sp[11] = softplus_f(v2.w);
    sp[12] = softplus_f(v3.x); sp[13] = softplus_f(v3.y);
    sp[14] = softplus_f(v3.z); sp[15] = softplus_f(v3.w);
    float r1 = 0.f;
#pragma unroll
    for (int k = 0; k < 16; ++k) r1 += sp[k];
    r1 += __shfl_xor(r1, 1, 64);
    r1 += __shfl_xor(r1, 2, 64);
    float inv1 = 1.0f / (r1 + EPS);
    float r2 = 0.f;
#pragma unroll
    for (int k = 0; k < 16; ++k) {
      sp[k] = fmaxf(sp[k] * inv1, EPS);
      r2 += sp[k];
    }
    r2 += __shfl_xor(r2, 1, 64);
    r2 += __shfl_xor(r2, 2, 64);
    float inv2 = 1.0f / (r2 + EPS);
    float* dst = (row < 64) ? &si[row * 68 + q * 16] : &sj[(row - 64) * 68 + q * 16];
#pragma unroll
    for (int k = 0; k < 16; ++k) dst[k] = sqrtf(sp[k] * inv2);
  } else {
#pragma unroll
    for (int k = 0; k < 2; ++k) {  // 1024 float4 per buffer over 512 threads
      int idx = tid + k * 512;
      int row = idx >> 4, q = idx & 15;
      *(float4*)&si[row * 68 + q * 4] =
          *(const float4*)(sb + (it * 64 + row) * D_ + q * 4);
      *(float4*)&sj[row * 68 + q * 4] =
          *(const float4*)(sb + (jt * 64 + row) * D_ + q * 4);
    }
  }
  __syncthreads();

  int dh = tid & 1, j4 = (tid >> 1) & 15, i4 = (tid >> 5) & 15;
  float acc[4][4];
#pragma unroll
  for (int a = 0; a < 4; ++a)
#pragma unroll
    for (int c = 0; c < 4; ++c) acc[a][c] = 0.f;

#pragma unroll
  for (int d4 = 0; d4 < 8; ++d4) {
    int db = dh * 32 + d4 * 4;
    float4 A[4], Bv[4];
#pragma unroll
    for (int a = 0; a < 4; ++a) A[a] = *(const float4*)&si[(i4 + 16 * a) * 68 + db];
#pragma unroll
    for (int c = 0; c < 4; ++c) Bv[c] = *(const float4*)&sj[(j4 + 16 * c) * 68 + db];
#pragma unroll
    for (int a = 0; a < 4; ++a)
#pragma unroll
      for (int c = 0; c < 4; ++c) {
        acc[a][c] = fmaf(A[a].x, Bv[c].x, acc[a][c]);
        acc[a][c] = fmaf(A[a].y, Bv[c].y, acc[a][c]);
        acc[a][c] = fmaf(A[a].z, Bv[c].z, acc[a][c]);
        acc[a][c] = fmaf(A[a].w, Bv[c].w, acc[a][c]);
      }
  }
#pragma unroll
  for (int a = 0; a < 4; ++a) {
    float* Lr = L + ((size_t)(b * T_) + it * 64 + i4 + 16 * a) * T_ + jt * 64;
#pragma unroll
    for (int c = 0; c < 4; ++c) {
      float v = acc[a][c] + __shfl_xor(acc[a][c], 1, 64);
      if (dh == 0) {
        float inner = fminf(fmaxf(v, 0.0f), 1.0f - 1e-6f);
        Lr[j4 + 16 * c] = -2.0f * acos_fast(inner);
      }
    }
  }
}

// ---- apply: row softmax + w@x + residual, 512 thr, 8 rows/block
//      !PART: fused next-iteration s;  PART: cov/mean/kappa partials ----
template <bool PART>
__global__ __launch_bounds__(512) void apply_kernel(
    const float* __restrict__ L, const float* __restrict__ xin,
    const float* __restrict__ rsp, float* __restrict__ xout,
    float* __restrict__ sout, float* __restrict__ covp,
    float* __restrict__ meanp, float* __restrict__ kappap) {
  int b = blockIdx.y, ic = blockIdx.x, i0 = ic * 8;
  __shared__ float wR[8 * 512];      // 16 KB normalized weights
  __shared__ float red[8 * 8 * 64];  // 16 KB cross-wave partials
  __shared__ float xf[8 * 68];
  __shared__ float kred[8];
  int tid = threadIdx.x;
  int w = tid >> 6, lane = tid & 63;

  {  // softmax: wave w owns row w
    const float* Lr = L + ((size_t)(b * T_) + i0 + w) * T_;
    float4 v0 = ((const float4*)Lr)[lane];
    float4 v1 = ((const float4*)Lr)[64 + lane];
    float m = fmaxf(fmaxf(fmaxf(v0.x, v0.y), fmaxf(v0.z, v0.w)),
                    fmaxf(fmaxf(v1.x, v1.y), fmaxf(v1.z, v1.w)));
    m = wave_max(m);
    float4 e0, e1;
    e0.x = __expf(v0.x - m); e0.y = __expf(v0.y - m);
    e0.z = __expf(v0.z - m); e0.w = __expf(v0.w - m);
    e1.x = __expf(v1.x - m); e1.y = __expf(v1.y - m);
    e1.z = __expf(v1.z - m); e1.w = __expf(v1.w - m);
    float ssum = wave_sum(e0.x + e0.y + e0.z + e0.w + e1.x + e1.y + e1.z + e1.w);
    float inv = 1.0f / ssum;
    e0.x *= inv; e0.y *= inv; e0.z *= inv; e0.w *= inv;
    e1.x *= inv; e1.y *= inv; e1.z *= inv; e1.w *= inv;
    ((float4*)&wR[w * 512])[lane] = e0;
    ((float4*)&wR[w * 512])[64 + lane] = e1;
  }
  __syncthreads();

  // w@x: thread = (dg: d-quad, js in [0,32)): 16 j's each
  int dg = tid & 15, js = tid >> 4;
  float acc[8][4];
#pragma unroll
  for (int i = 0; i < 8; ++i)
#pragma unroll
    for (int k = 0; k < 4; ++k) acc[i][k] = 0.f;
  const float* xb = xin + (size_t)(b * T_) * D_;
#pragma unroll
  for (int jj = 0; jj < 4; ++jj) {
    int jbase = js * 16 + jj * 4;
    float xr[4][4];
#pragma unroll
    for (int c = 0; c < 4; ++c) {
      float4 xv = *(const float4*)(xb + (jbase + c) * D_ + dg * 4);
      xr[c][0] = xv.x; xr[c][1] = xv.y; xr[c][2] = xv.z; xr[c][3] = xv.w;
    }
#pragma unroll
    for (int i = 0; i < 8; ++i) {
      float4 wv = *(const float4*)&wR[i * 512 + jbase];
      float wc[4] = {wv.x, wv.y, wv.z, wv.w};
#pragma unroll
      for (int c = 0; c < 4; ++c)
#pragma unroll
        for (int k = 0; k < 4; ++k)
          acc[i][k] = fmaf(wc[c], xr[c][k], acc[i][k]);
    }
  }
  // reduce js low-2 bits (lane bits 4,5); lanes<16 hold the wave partial
#pragma unroll
  for (int i = 0; i < 8; ++i)
#pragma unroll
    for (int k = 0; k < 4; ++k) {
      float v = acc[i][k];
      v += __shfl_xor(v, 16, 64);
      v += __shfl_xor(v, 32, 64);
      acc[i][k] = v;
    }
  if (lane < 16) {
#pragma unroll
    for (int i = 0; i < 8; ++i)
      *(float4*)&red[(w * 8 + i) * 64 + lane * 4] =
          make_float4(acc[i][0], acc[i][1], acc[i][2], acc[i][3]);
  }
  __syncthreads();

  // residual: wave w owns row w
  float c01 = 0.01f * rsp[0];
  {
    int i = w, d = lane;
    float xa = 0.f;
#pragma unroll
    for (int ww = 0; ww < 8; ++ww) xa += red[(ww * 8 + i) * 64 + d];
    size_t idx = ((size_t)(b * T_) + i0 + i) * D_ + d;
    float xn = 0.5f * (1.0f - c01) * xin[idx] + 0.5f * (1.0f + c01) * xa;
    xout[idx] = xn;
    if (!PART) {
      float sp = softplus_f(xn);
      float s1 = wave_sum(sp);
      float p = sp / (s1 + EPS);
      p = fmaxf(p, EPS);
      float s2 = wave_sum(p);
      sout[idx] = sqrtf(p / (s2 + EPS));
    } else {
      xf[i * 68 + d] = xn;
      float ssq = wave_sum(xn * xn);
      if (lane == 0) kred[w] = sqrtf(ssq);
    }
  }
  if (PART) {
    __syncthreads();
    // cov partial over this block's 8 rows: thread = (dd, e8: 8 e's)
    int dd = tid >> 3, e8 = tid & 7;
    float ac[8];
#pragma unroll
    for (int k = 0; k < 8; ++k) ac[k] = 0.f;
#pragma unroll
    for (int t = 0; t < 8; ++t) {
      float xd = xf[t * 68 + dd];
      const float4* te = (const float4*)&xf[t * 68 + e8 * 8];
      float4 v0 = te[0], v1 = te[1];
      ac[0] = fmaf(xd, v0.x, ac[0]); ac[1] = fmaf(xd, v0.y, ac[1]);
      ac[2] = fmaf(xd, v0.z, ac[2]); ac[3] = fmaf(xd, v0.w, ac[3]);
      ac[4] = fmaf(xd, v1.x, ac[4]); ac[5] = fmaf(xd, v1.y, ac[5]);
      ac[6] = fmaf(xd, v1.z, ac[6]); ac[7] = fmaf(xd, v1.w, ac[7]);
    }
    float* cp = covp + ((size_t)(b * 64 + ic)) * 4096 + dd * 64 + e8 * 8;
    *(float4*)cp = make_float4(ac[0], ac[1], ac[2], ac[3]);
    *(float4*)(cp + 4) = make_float4(ac[4], ac[5], ac[6], ac[7]);
    if (tid < 64) {
      float m = 0.f;
#pragma unroll
      for (int t = 0; t < 8; ++t) m += xf[t * 68 + tid];
      meanp[(b * 64 + ic) * 64 + tid] = m;
    }
    if (tid == 0) {
      float kk = 0.f;
#pragma unroll
      for (int ww = 0; ww < 8; ++ww) kk += kred[ww];
      kappap[b * 64 + ic] = kk;
    }
  }
}

// ---- finalize phi + kappa per batch (reduces 64 slices) ----
__global__ __launch_bounds__(256) void p2_kernel(const float* __restrict__ covp,
                                                 const float* __restrict__ meanp,
                                                 const float* __restrict__ kappap,
                                                 float* __restrict__ out) {
  int b = blockIdx.x;
  __shared__ float mu[64];
  __shared__ float var[64];
  __shared__ float phired[4];
  int tid = threadIdx.x;
  if (tid < 64) {
    float m = 0.f;
    for (int s = 0; s < 64; ++s) m += meanp[(b * 64 + s) * 64 + tid];
    mu[tid] = m * (1.0f / 512.0f);
  }
  __syncthreads();

  int dd = tid >> 2, e16 = tid & 3;
  float acc[16];
#pragma unroll
  for (int k = 0; k < 16; ++k) acc[k] = 0.f;
  for (int s = 0; s < 64; ++s) {
    const float* cp = covp + ((size_t)(b * 64 + s)) * 4096 + dd * 64 + e16 * 16;
#pragma unroll
    for (int kk = 0; kk < 4; ++kk) {
      float4 v = *(const float4*)(cp + kk * 4);
      acc[kk * 4] += v.x; acc[kk * 4 + 1] += v.y;
      acc[kk * 4 + 2] += v.z; acc[kk * 4 + 3] += v.w;
    }
  }
  float mud = mu[dd];
#pragma unroll
  for (int k = 0; k < 16; ++k)
    acc[k] = acc[k] * (1.0f / 512.0f) - mud * mu[e16 * 16 + k];
  if ((dd >> 4) == e16) var[dd] = fmaxf(acc[dd & 15], EPS);
  __syncthreads();

  float vd = var[dd];
  float psum = 0.f;
#pragma unroll
  for (int k = 0; k < 16; ++k) {
    int e = e16 * 16 + k;
    if (e == dd) continue;
    float denom = fmaxf(sqrtf(vd * var[e]), EPS);
    float cc = fminf(fmaxf(acc[k] / denom, -1.0f), 1.0f);
    psum += fabsf(cc);
  }
  psum = wave_sum(psum);
  if ((tid & 63) == 0) phired[tid >> 6] = psum;
  __syncthreads();
  if (tid == 0) {
    out[B_ * T_ * D_ + b] = (phired[0] + phired[1] + phired[2] + phired[3]) *
                            (1.0f / 4096.0f);
    float ks = 0.f;
    for (int s = 0; s < 64; ++s) ks += kappap[b * 64 + s];
    out[B_ * T_ * D_ + B_ + b] = ks * (1.0f / 512.0f);
  }
}

extern "C" void kernel_launch(void* const* d_in, const int* in_sizes, int n_in,
                              void* d_out, int out_size, void* d_ws, size_t ws_size,
                              hipStream_t stream) {
  const float* x0 = (const float*)d_in[0];
  const float* rs = (const float*)d_in[1];
  float* out = (float*)d_out;
  float* s2 = (float*)d_ws;              // 131072 floats
  float* x1 = s2 + 131072;               // 131072
  float* L = x1 + 131072;                // 1048576
  float* covp = L + 1048576;             // 256*4096
  float* meanp = covp + 256 * 4096;      // 16384
  float* kappap = meanp + 16384;         // 256

  dim3 lgrd(8, 8, B_), agrd(64, B_);
  logits_kernel<true><<<lgrd, 512, 0, stream>>>(x0, L);   // s from x0 in-kernel
  apply_kernel<false><<<agrd, 512, 0, stream>>>(L, x0, rs, x1, s2, covp, meanp, kappap);
  logits_kernel<false><<<lgrd, 512, 0, stream>>>(s2, L);  // s2 precomputed
  apply_kernel<true><<<agrd, 512, 0, stream>>>(L, x1, rs, out, s2, covp, meanp, kappap);
  p2_kernel<<<B_, 256, 0, stream>>>(covp, meanp, kappap, out);
}

// Round 6
// 105.923 us; speedup vs baseline: 1.1511x; 1.1511x over previous
//
#include <hip/hip_runtime.h>
#include <math.h>

#define B_ 4
#define T_ 512
#define D_ 64
#define EPS 1e-8f

__device__ __forceinline__ float wave_sum(float v) {
#pragma unroll
  for (int m = 1; m < 64; m <<= 1) v += __shfl_xor(v, m, 64);
  return v;
}
__device__ __forceinline__ float wave_max(float v) {
#pragma unroll
  for (int m = 1; m < 64; m <<= 1) v = fmaxf(v, __shfl_xor(v, m, 64));
  return v;
}
__device__ __forceinline__ float softplus_f(float x) {
  return fmaxf(x, 0.0f) + __logf(1.0f + __expf(-fabsf(x)));
}
// acos(x), x in [0,1): A&S 4.4.45, |err| <= 6.8e-5 rad.
__device__ __forceinline__ float acos_fast(float x) {
  float r = fmaf(x, -0.0187293f, 0.0742610f);
  r = fmaf(r, x, -0.2121144f);
  r = fmaf(r, x, 1.5707288f);
  return r * sqrtf(1.0f - x);
}

// ---- logits: 64x64 tile of -2*acos(clip(s_i . s_j)), 512 thr (8 waves) ----
// COMPUTE_S: derive the needed 128 s-rows from x in-kernel (saves the proj
// launch); else read precomputed s. GEMM: thread=(dh,j4,i4), 4x4 reg tile
// over 32 d, shfl_xor(1) combines d-halves.
template <bool COMPUTE_S>
__global__ __launch_bounds__(512) void logits_kernel(const float* __restrict__ xs,
                                                     float* __restrict__ L) {
  int jt = blockIdx.x, it = blockIdx.y, b = blockIdx.z;
  __shared__ float si[64 * 68];
  __shared__ float sj[64 * 68];
  int tid = threadIdx.x;
  const float* sb = xs + (size_t)b * T_ * D_;

  if (COMPUTE_S) {
    // thread = (row 0..127, q: d-quarter). softplus + double-normalize.
    int row = tid >> 2, q = tid & 3;
    int grow = (row < 64) ? (it * 64 + row) : (jt * 64 + (row - 64));
    const float4* xr = (const float4*)(sb + grow * D_ + q * 16);
    float sp[16];
    float4 v0 = xr[0], v1 = xr[1], v2 = xr[2], v3 = xr[3];
    sp[0] = softplus_f(v0.x); sp[1] = softplus_f(v0.y);
    sp[2] = softplus_f(v0.z); sp[3] = softplus_f(v0.w);
    sp[4] = softplus_f(v1.x); sp[5] = softplus_f(v1.y);
    sp[6] = softplus_f(v1.z); sp[7] = softplus_f(v1.w);
    sp[8] = softplus_f(v2.x); sp[9] = softplus_f(v2.y);
    sp[10] = softplus_f(v2.z); sp[11] = softplus_f(v2.w);
    sp[12] = softplus_f(v3.x); sp[13] = softplus_f(v3.y);
    sp[14] = softplus_f(v3.z); sp[15] = softplus_f(v3.w);
    float r1 = 0.f;
#pragma unroll
    for (int k = 0; k < 16; ++k) r1 += sp[k];
    r1 += __shfl_xor(r1, 1, 64);
    r1 += __shfl_xor(r1, 2, 64);
    float inv1 = 1.0f / (r1 + EPS);
    float r2 = 0.f;
#pragma unroll
    for (int k = 0; k < 16; ++k) {
      sp[k] = fmaxf(sp[k] * inv1, EPS);
      r2 += sp[k];
    }
    r2 += __shfl_xor(r2, 1, 64);
    r2 += __shfl_xor(r2, 2, 64);
    float inv2 = 1.0f / (r2 + EPS);
    float* dst = (row < 64) ? &si[row * 68 + q * 16] : &sj[(row - 64) * 68 + q * 16];
#pragma unroll
    for (int k = 0; k < 16; ++k) dst[k] = sqrtf(sp[k] * inv2);
  } else {
#pragma unroll
    for (int k = 0; k < 2; ++k) {  // 1024 float4 per buffer over 512 threads
      int idx = tid + k * 512;
      int row = idx >> 4, q = idx & 15;
      *(float4*)&si[row * 68 + q * 4] =
          *(const float4*)(sb + (it * 64 + row) * D_ + q * 4);
      *(float4*)&sj[row * 68 + q * 4] =
          *(const float4*)(sb + (jt * 64 + row) * D_ + q * 4);
    }
  }
  __syncthreads();

  int dh = tid & 1, j4 = (tid >> 1) & 15, i4 = (tid >> 5) & 15;
  float acc[4][4];
#pragma unroll
  for (int a = 0; a < 4; ++a)
#pragma unroll
    for (int c = 0; c < 4; ++c) acc[a][c] = 0.f;

#pragma unroll
  for (int d4 = 0; d4 < 8; ++d4) {
    int db = dh * 32 + d4 * 4;
    float4 A[4], Bv[4];
#pragma unroll
    for (int a = 0; a < 4; ++a) A[a] = *(const float4*)&si[(i4 + 16 * a) * 68 + db];
#pragma unroll
    for (int c = 0; c < 4; ++c) Bv[c] = *(const float4*)&sj[(j4 + 16 * c) * 68 + db];
#pragma unroll
    for (int a = 0; a < 4; ++a)
#pragma unroll
      for (int c = 0; c < 4; ++c) {
        acc[a][c] = fmaf(A[a].x, Bv[c].x, acc[a][c]);
        acc[a][c] = fmaf(A[a].y, Bv[c].y, acc[a][c]);
        acc[a][c] = fmaf(A[a].z, Bv[c].z, acc[a][c]);
        acc[a][c] = fmaf(A[a].w, Bv[c].w, acc[a][c]);
      }
  }
#pragma unroll
  for (int a = 0; a < 4; ++a) {
    float* Lr = L + ((size_t)(b * T_) + it * 64 + i4 + 16 * a) * T_ + jt * 64;
#pragma unroll
    for (int c = 0; c < 4; ++c) {
      float v = acc[a][c] + __shfl_xor(acc[a][c], 1, 64);
      if (dh == 0) {
        float inner = fminf(fmaxf(v, 0.0f), 1.0f - 1e-6f);
        Lr[j4 + 16 * c] = -2.0f * acos_fast(inner);
      }
    }
  }
}

// ---- apply: row softmax + w@x + residual, 512 thr, 8 rows/block
//      !PART: fused next-iteration s;  PART: cov/mean/kappa partials ----
template <bool PART>
__global__ __launch_bounds__(512) void apply_kernel(
    const float* __restrict__ L, const float* __restrict__ xin,
    const float* __restrict__ rsp, float* __restrict__ xout,
    float* __restrict__ sout, float* __restrict__ covp,
    float* __restrict__ meanp, float* __restrict__ kappap) {
  int b = blockIdx.y, ic = blockIdx.x, i0 = ic * 8;
  __shared__ float wR[8 * 512];      // 16 KB normalized weights
  __shared__ float red[8 * 8 * 64];  // 16 KB cross-wave partials
  __shared__ float xf[8 * 68];
  __shared__ float kred[8];
  int tid = threadIdx.x;
  int w = tid >> 6, lane = tid & 63;

  {  // softmax: wave w owns row w
    const float* Lr = L + ((size_t)(b * T_) + i0 + w) * T_;
    float4 v0 = ((const float4*)Lr)[lane];
    float4 v1 = ((const float4*)Lr)[64 + lane];
    float m = fmaxf(fmaxf(fmaxf(v0.x, v0.y), fmaxf(v0.z, v0.w)),
                    fmaxf(fmaxf(v1.x, v1.y), fmaxf(v1.z, v1.w)));
    m = wave_max(m);
    float4 e0, e1;
    e0.x = __expf(v0.x - m); e0.y = __expf(v0.y - m);
    e0.z = __expf(v0.z - m); e0.w = __expf(v0.w - m);
    e1.x = __expf(v1.x - m); e1.y = __expf(v1.y - m);
    e1.z = __expf(v1.z - m); e1.w = __expf(v1.w - m);
    float ssum = wave_sum(e0.x + e0.y + e0.z + e0.w + e1.x + e1.y + e1.z + e1.w);
    float inv = 1.0f / ssum;
    e0.x *= inv; e0.y *= inv; e0.z *= inv; e0.w *= inv;
    e1.x *= inv; e1.y *= inv; e1.z *= inv; e1.w *= inv;
    ((float4*)&wR[w * 512])[lane] = e0;
    ((float4*)&wR[w * 512])[64 + lane] = e1;
  }
  __syncthreads();

  // w@x: thread = (dg: d-quad, js in [0,32)): 16 j's each
  int dg = tid & 15, js = tid >> 4;
  float acc[8][4];
#pragma unroll
  for (int i = 0; i < 8; ++i)
#pragma unroll
    for (int k = 0; k < 4; ++k) acc[i][k] = 0.f;
  const float* xb = xin + (size_t)(b * T_) * D_;
#pragma unroll
  for (int jj = 0; jj < 4; ++jj) {
    int jbase = js * 16 + jj * 4;
    float xr[4][4];
#pragma unroll
    for (int c = 0; c < 4; ++c) {
      float4 xv = *(const float4*)(xb + (jbase + c) * D_ + dg * 4);
      xr[c][0] = xv.x; xr[c][1] = xv.y; xr[c][2] = xv.z; xr[c][3] = xv.w;
    }
#pragma unroll
    for (int i = 0; i < 8; ++i) {
      float4 wv = *(const float4*)&wR[i * 512 + jbase];
      float wc[4] = {wv.x, wv.y, wv.z, wv.w};
#pragma unroll
      for (int c = 0; c < 4; ++c)
#pragma unroll
        for (int k = 0; k < 4; ++k)
          acc[i][k] = fmaf(wc[c], xr[c][k], acc[i][k]);
    }
  }
  // reduce js low-2 bits (lane bits 4,5); lanes<16 hold the wave partial
#pragma unroll
  for (int i = 0; i < 8; ++i)
#pragma unroll
    for (int k = 0; k < 4; ++k) {
      float v = acc[i][k];
      v += __shfl_xor(v, 16, 64);
      v += __shfl_xor(v, 32, 64);
      acc[i][k] = v;
    }
  if (lane < 16) {
#pragma unroll
    for (int i = 0; i < 8; ++i)
      *(float4*)&red[(w * 8 + i) * 64 + lane * 4] =
          make_float4(acc[i][0], acc[i][1], acc[i][2], acc[i][3]);
  }
  __syncthreads();

  // residual: wave w owns row w
  float c01 = 0.01f * rsp[0];
  {
    int i = w, d = lane;
    float xa = 0.f;
#pragma unroll
    for (int ww = 0; ww < 8; ++ww) xa += red[(ww * 8 + i) * 64 + d];
    size_t idx = ((size_t)(b * T_) + i0 + i) * D_ + d;
    float xn = 0.5f * (1.0f - c01) * xin[idx] + 0.5f * (1.0f + c01) * xa;
    xout[idx] = xn;
    if (!PART) {
      float sp = softplus_f(xn);
      float s1 = wave_sum(sp);
      float p = sp / (s1 + EPS);
      p = fmaxf(p, EPS);
      float s2 = wave_sum(p);
      sout[idx] = sqrtf(p / (s2 + EPS));
    } else {
      xf[i * 68 + d] = xn;
      float ssq = wave_sum(xn * xn);
      if (lane == 0) kred[w] = sqrtf(ssq);
    }
  }
  if (PART) {
    __syncthreads();
    // cov partial over this block's 8 rows: thread = (dd, e8: 8 e's)
    int dd = tid >> 3, e8 = tid & 7;
    float ac[8];
#pragma unroll
    for (int k = 0; k < 8; ++k) ac[k] = 0.f;
#pragma unroll
    for (int t = 0; t < 8; ++t) {
      float xd = xf[t * 68 + dd];
      const float4* te = (const float4*)&xf[t * 68 + e8 * 8];
      float4 v0 = te[0], v1 = te[1];
      ac[0] = fmaf(xd, v0.x, ac[0]); ac[1] = fmaf(xd, v0.y, ac[1]);
      ac[2] = fmaf(xd, v0.z, ac[2]); ac[3] = fmaf(xd, v0.w, ac[3]);
      ac[4] = fmaf(xd, v1.x, ac[4]); ac[5] = fmaf(xd, v1.y, ac[5]);
      ac[6] = fmaf(xd, v1.z, ac[6]); ac[7] = fmaf(xd, v1.w, ac[7]);
    }
    float* cp = covp + ((size_t)(b * 64 + ic)) * 4096 + dd * 64 + e8 * 8;
    *(float4*)cp = make_float4(ac[0], ac[1], ac[2], ac[3]);
    *(float4*)(cp + 4) = make_float4(ac[4], ac[5], ac[6], ac[7]);
    if (tid < 64) {
      float m = 0.f;
#pragma unroll
      for (int t = 0; t < 8; ++t) m += xf[t * 68 + tid];
      meanp[(b * 64 + ic) * 64 + tid] = m;
    }
    if (tid == 0) {
      float kk = 0.f;
#pragma unroll
      for (int ww = 0; ww < 8; ++ww) kk += kred[ww];
      kappap[b * 64 + ic] = kk;
    }
  }
}

// ---- p2a: 256 slices -> 32 (8 each) — wide first-stage reduction ----
__global__ __launch_bounds__(256) void p2a_kernel(
    const float* __restrict__ covp, const float* __restrict__ meanp,
    const float* __restrict__ kappap, float* __restrict__ covq,
    float* __restrict__ meanq, float* __restrict__ kappaq) {
  int blk = blockIdx.x;
  int b = blk >> 3, g = blk & 7;
  int tid = threadIdx.x;
  int dd = tid >> 2, e16 = tid & 3;
  float ac[16];
#pragma unroll
  for (int k = 0; k < 16; ++k) ac[k] = 0.f;
#pragma unroll
  for (int s = 0; s < 8; ++s) {
    const float* cp =
        covp + ((size_t)(b * 64 + g * 8 + s)) * 4096 + dd * 64 + e16 * 16;
#pragma unroll
    for (int kk = 0; kk < 4; ++kk) {
      float4 v = *(const float4*)(cp + kk * 4);
      ac[kk * 4] += v.x; ac[kk * 4 + 1] += v.y;
      ac[kk * 4 + 2] += v.z; ac[kk * 4 + 3] += v.w;
    }
  }
  float* cq = covq + (size_t)blk * 4096 + dd * 64 + e16 * 16;
#pragma unroll
  for (int kk = 0; kk < 4; ++kk)
    *(float4*)(cq + kk * 4) =
        make_float4(ac[kk * 4], ac[kk * 4 + 1], ac[kk * 4 + 2], ac[kk * 4 + 3]);
  if (tid < 64) {
    float m = 0.f;
#pragma unroll
    for (int s = 0; s < 8; ++s) m += meanp[(b * 64 + g * 8 + s) * 64 + tid];
    meanq[blk * 64 + tid] = m;
  }
  if (tid == 0) {
    float k = 0.f;
#pragma unroll
    for (int s = 0; s < 8; ++s) k += kappap[b * 64 + g * 8 + s];
    kappaq[blk] = k;
  }
}

// ---- p2b: finalize phi + kappa per batch (8 slices) ----
__global__ __launch_bounds__(256) void p2b_kernel(
    const float* __restrict__ covq, const float* __restrict__ meanq,
    const float* __restrict__ kappaq, float* __restrict__ out) {
  int b = blockIdx.x;
  __shared__ float mu[64];
  __shared__ float var[64];
  __shared__ float phired[4];
  int tid = threadIdx.x;
  if (tid < 64) {
    float m = 0.f;
#pragma unroll
    for (int s = 0; s < 8; ++s) m += meanq[(b * 8 + s) * 64 + tid];
    mu[tid] = m * (1.0f / 512.0f);
  }
  __syncthreads();

  int dd = tid >> 2, e16 = tid & 3;
  float acc[16];
#pragma unroll
  for (int k = 0; k < 16; ++k) acc[k] = 0.f;
#pragma unroll
  for (int s = 0; s < 8; ++s) {
    const float* cp = covq + ((size_t)(b * 8 + s)) * 4096 + dd * 64 + e16 * 16;
#pragma unroll
    for (int kk = 0; kk < 4; ++kk) {
      float4 v = *(const float4*)(cp + kk * 4);
      acc[kk * 4] += v.x; acc[kk * 4 + 1] += v.y;
      acc[kk * 4 + 2] += v.z; acc[kk * 4 + 3] += v.w;
    }
  }
  float mud = mu[dd];
#pragma unroll
  for (int k = 0; k < 16; ++k)
    acc[k] = acc[k] * (1.0f / 512.0f) - mud * mu[e16 * 16 + k];
  if ((dd >> 4) == e16) var[dd] = fmaxf(acc[dd & 15], EPS);
  __syncthreads();

  float vd = var[dd];
  float psum = 0.f;
#pragma unroll
  for (int k = 0; k < 16; ++k) {
    int e = e16 * 16 + k;
    if (e == dd) continue;
    float denom = fmaxf(sqrtf(vd * var[e]), EPS);
    float cc = fminf(fmaxf(acc[k] / denom, -1.0f), 1.0f);
    psum += fabsf(cc);
  }
  psum = wave_sum(psum);
  if ((tid & 63) == 0) phired[tid >> 6] = psum;
  __syncthreads();
  if (tid == 0) {
    out[B_ * T_ * D_ + b] = (phired[0] + phired[1] + phired[2] + phired[3]) *
                            (1.0f / 4096.0f);
    float ks = 0.f;
#pragma unroll
    for (int s = 0; s < 8; ++s) ks += kappaq[b * 8 + s];
    out[B_ * T_ * D_ + B_ + b] = ks * (1.0f / 512.0f);
  }
}

extern "C" void kernel_launch(void* const* d_in, const int* in_sizes, int n_in,
                              void* d_out, int out_size, void* d_ws, size_t ws_size,
                              hipStream_t stream) {
  const float* x0 = (const float*)d_in[0];
  const float* rs = (const float*)d_in[1];
  float* out = (float*)d_out;
  float* s2 = (float*)d_ws;              // 131072 floats
  float* x1 = s2 + 131072;               // 131072
  float* L = x1 + 131072;                // 1048576
  float* covp = L + 1048576;             // 256*4096
  float* meanp = covp + 256 * 4096;      // 16384
  float* kappap = meanp + 16384;         // 256
  float* covq = kappap + 256;            // 32*4096
  float* meanq = covq + 32 * 4096;       // 2048
  float* kappaq = meanq + 2048;          // 32

  dim3 lgrd(8, 8, B_), agrd(64, B_);
  logits_kernel<true><<<lgrd, 512, 0, stream>>>(x0, L);   // s from x0 in-kernel
  apply_kernel<false><<<agrd, 512, 0, stream>>>(L, x0, rs, x1, s2, covp, meanp, kappap);
  logits_kernel<false><<<lgrd, 512, 0, stream>>>(s2, L);  // s2 precomputed
  apply_kernel<true><<<agrd, 512, 0, stream>>>(L, x1, rs, out, s2, covp, meanp, kappap);
  p2a_kernel<<<32, 256, 0, stream>>>(covp, meanp, kappap, covq, meanq, kappaq);
  p2b_kernel<<<B_, 256, 0, stream>>>(covq, meanq, kappaq, out);
}